// Round 7
// baseline (12704.150 us; speedup 1.0000x reference)
//
#include <hip/hip_runtime.h>
#include <math.h>

#define B_SZ   32
#define T_SZ   1024
#define IN_SZ  512
#define SEN    512
#define HID    1024
#define MOT    512
#define OUT_SZ 512

#define NBLK   32          // scan blocks (j-slices)
#define JSL    32          // j's per block
#define K2     512         // f16-pair words per h row
#define HPAD   516         // padded h_lds row stride (dwords)
#define WPAD   516         // padded w_lds row stride (dwords)

typedef __fp16 h2_t __attribute__((ext_vector_type(2)));

__device__ inline float fd2(uint32_t a, uint32_t b, float c) {
  h2_t ha = __builtin_bit_cast(h2_t, a);
  h2_t hb = __builtin_bit_cast(h2_t, b);
  return __builtin_amdgcn_fdot2(ha, hb, c, false);
}

__device__ inline uint32_t pk16(float a, float b) {
  auto p = __builtin_amdgcn_cvt_pkrtz(a, b);
  return __builtin_bit_cast(uint32_t, p);
}

// ---------------------------------------------------------------------------
// Generic tiled f32 GEMM:  C[scatter(r), c] = sum_k A[r,k] * op(B)[k,c] + bias[c]
//   TB=true : Bm is [N][K] row-major (A @ B^T);  TB=false: Bm is [K][N] (A @ B)
//   C address for row r, col c:  (r % P)*S1 + (r / P)*S2 + c
// ---------------------------------------------------------------------------
template<bool TB>
__global__ __launch_bounds__(256) void gemm_tiled(
    const float* __restrict__ A, const float* __restrict__ Bm,
    const float* __restrict__ bias, float* __restrict__ C,
    int M, int N, int K, int lda,
    int P, long long S1, long long S2)
{
  __shared__ float As[16][64 + 1];
  __shared__ float Bs[16][64 + 1];
  const int tid = threadIdx.x;
  const int n0 = blockIdx.x * 64;
  const int r0 = blockIdx.y * 64;
  const int ty = tid / 16;
  const int tx = tid % 16;

  float acc[4][4] = {};

  for (int k0 = 0; k0 < K; k0 += 16) {
    {
      const int kk = tid % 16, m0 = tid / 16;
      #pragma unroll
      for (int i = 0; i < 4; i++) {
        const int m = m0 + i * 16;
        As[kk][m] = A[(long long)(r0 + m) * lda + k0 + kk];
      }
    }
    if (TB) {
      const int kk = tid % 16, nl0 = tid / 16;
      #pragma unroll
      for (int i = 0; i < 4; i++) {
        const int n = nl0 + i * 16;
        Bs[kk][n] = Bm[(long long)(n0 + n) * K + k0 + kk];
      }
    } else {
      const int nl = tid % 64, kk0 = tid / 64;
      #pragma unroll
      for (int i = 0; i < 4; i++) {
        const int kk = kk0 + i * 4;
        Bs[kk][nl] = Bm[(long long)(k0 + kk) * N + n0 + nl];
      }
    }
    __syncthreads();

    #pragma unroll
    for (int kk = 0; kk < 16; kk++) {
      float av[4], bv[4];
      #pragma unroll
      for (int i = 0; i < 4; i++) av[i] = As[kk][ty * 4 + i];
      #pragma unroll
      for (int j = 0; j < 4; j++) bv[j] = Bs[kk][tx * 4 + j];
      #pragma unroll
      for (int i = 0; i < 4; i++)
        #pragma unroll
        for (int j = 0; j < 4; j++)
          acc[i][j] += av[i] * bv[j];
    }
    __syncthreads();
  }

  #pragma unroll
  for (int i = 0; i < 4; i++) {
    const int r = r0 + ty * 4 + i;
    const long long base = (long long)(r % P) * S1 + (long long)(r / P) * S2;
    #pragma unroll
    for (int j = 0; j < 4; j++) {
      const int c = n0 + tx * 4 + j;
      float v = acc[i][j];
      if (bias) v += bias[c];
      C[base + c] = v;
    }
  }
}

// bias_eff[h] = b_cell[h] + dot(W_x[h,:], b_in)
__global__ void bias_eff_kernel(const float* __restrict__ Wx,
                                const float* __restrict__ b_in,
                                const float* __restrict__ b_cell,
                                float* __restrict__ bias_eff)
{
  const int h = blockIdx.x * 256 + threadIdx.x;
  float s = b_cell[h];
  for (int k = 0; k < SEN; k++) s += Wx[h * SEN + k] * b_in[k];
  bias_eff[h] = s;
}

// Pack W_h f32 [j][k] -> Wp16 u32 [j][k2]: pack(f16(W[j][2k2]), f16(W[j][2k2+1]))
__global__ __launch_bounds__(256) void pack_wh16_kernel(
    const float* __restrict__ Wh, uint32_t* __restrict__ Wp16)
{
  const int idx = blockIdx.x * 256 + threadIdx.x;       // j*K2 + k2
  const float2 v = *(const float2*)(Wh + (size_t)idx * 2);
  Wp16[idx] = pk16(v.x, v.y);
}

// ---------------------------------------------------------------------------
// Scan v5: 32 blocks x 512 threads, j-sliced, W_h slice resident in LDS.
// Thread mapping (NEW): b = tid>>4, jg = tid&15  ->  hx / hseq / pre / last
// accesses are lane-contiguous (64-128B runs, no 32B-granule amplification).
// Barrier (NEW): per-block flag line + parallel 32-lane poll; no counter RMW
// serialization, no cache-wide fences. hx double-buffered by step parity.
// ---------------------------------------------------------------------------
__global__ __launch_bounds__(512) void scan_x_kernel(
    const float* __restrict__ init_h,
    const uint32_t* __restrict__ Wp16,   // [HID][K2]
    const float* __restrict__ pre,       // [T][B][HID]
    const float* __restrict__ tsp,       // [B][T]
    const float* __restrict__ Avec,
    const float* __restrict__ tau,
    float* __restrict__ hseq,            // [T][B][MOT]
    uint32_t* __restrict__ hx,           // [2][B][K2] exchange
    uint32_t* __restrict__ flags,        // [NBLK][16] arrival flags (pre-zeroed)
    float* __restrict__ last_state)      // [B][HID]
{
  __shared__ uint32_t w_lds[JSL * WPAD];   // 66 KB (padded rows)
  __shared__ uint32_t h_lds[B_SZ * HPAD];  // 66 KB

  const int bk  = blockIdx.x;
  const int tid = threadIdx.x;
  const int b   = tid >> 4;                // 0..31
  const int jg  = tid & 15;                // 0..15
  const int j0  = bk * JSL + 2 * jg;

  // stage weight slice (once), row-padded
  {
    const uint32_t* src = Wp16 + (size_t)bk * JSL * K2;
    for (int i = tid; i < JSL * K2; i += 512)
      w_lds[(i >> 9) * WPAD + (i & (K2 - 1))] = src[i];
  }
  // stage initial h (f32 -> f16x2)
  for (int i = tid; i < B_SZ * K2; i += 512) {
    const int bb = i >> 9, k2 = i & (K2 - 1);
    const float2 v = *(const float2*)(init_h + bb * HID + 2 * k2);
    h_lds[bb * HPAD + k2] = pk16(v.x, v.y);
  }

  const float2 apair = *(const float2*)(Avec + j0);
  const float2 tpair = *(const float2*)(tau + j0);
  const float it0 = 1.f / tpair.x, it1 = 1.f / tpair.y;
  float2 hreg = *(const float2*)(init_h + b * HID + j0);

  __syncthreads();

  const uint32_t* hrow  = &h_lds[b * HPAD];
  const uint32_t* wrow0 = &w_lds[(2 * jg) * WPAD];
  const uint32_t* wrow1 = &w_lds[(2 * jg + 1) * WPAD];

  // prefetch step-0 inputs
  float2 prevC = *(const float2*)(pre + (size_t)b * HID + j0);
  float  tsC   = tsp[b * T_SZ + 0];

  for (int t = 0; t < T_SZ; ++t) {
    float a00 = 0.f, a01 = 0.f, a10 = 0.f, a11 = 0.f;
    #pragma unroll 4
    for (int c = 0; c < K2 / 4; ++c) {
      const uint4 hv = *(const uint4*)(hrow + 4 * c);    // 4-addr broadcast
      const uint4 w0 = *(const uint4*)(wrow0 + 4 * c);   // 16 rows, padded
      const uint4 w1 = *(const uint4*)(wrow1 + 4 * c);
      a00 = fd2(hv.x, w0.x, a00); a01 = fd2(hv.y, w0.y, a01);
      a00 = fd2(hv.z, w0.z, a00); a01 = fd2(hv.w, w0.w, a01);
      a10 = fd2(hv.x, w1.x, a10); a11 = fd2(hv.y, w1.y, a11);
      a10 = fd2(hv.z, w1.z, a10); a11 = fd2(hv.w, w1.w, a11);
    }
    const float z0 = (a00 + a01) + prevC.x;
    const float z1 = (a10 + a11) + prevC.y;
    const float f0 = 1.f / (1.f + __expf(-z0));
    const float f1 = 1.f / (1.f + __expf(-z1));
    const float hn0 = (hreg.x + tsC * f0 * apair.x) / (1.f + tsC * (it0 + f0));
    const float hn1 = (hreg.y + tsC * f1 * apair.y) / (1.f + tsC * (it1 + f1));
    hreg.x = hn0; hreg.y = hn1;

    // publish own h dword — lane-contiguous 64B per 16-lane group
    uint32_t* hxw = hx + ((t + 1) & 1) * (B_SZ * K2);
    __hip_atomic_store(&hxw[b * K2 + bk * (JSL / 2) + jg], pk16(hn0, hn1),
                       __ATOMIC_RELAXED, __HIP_MEMORY_SCOPE_AGENT);

    __syncthreads();   // drains vmcnt(0): hx stores globally visible

    // arrival: one relaxed store to own flag line (no RMW serialization)
    if (tid == 0)
      __hip_atomic_store(&flags[bk * 16], (uint32_t)(t + 1),
                         __ATOMIC_RELAXED, __HIP_MEMORY_SCOPE_AGENT);

    // overlap with poll: hseq store + next-step prefetch (coalesced now)
    if (bk < 16)
      *(float2*)(hseq + (size_t)t * (B_SZ * MOT) + b * MOT + j0) = make_float2(hn0, hn1);
    const int tn = (t + 1 < T_SZ) ? t + 1 : t;
    prevC = *(const float2*)(pre + (size_t)tn * (B_SZ * HID) + b * HID + j0);
    tsC   = tsp[b * T_SZ + tn];

    // poll: wave 0 lanes watch all 32 flags in parallel
    if (tid < 64) {
      const uint32_t tgt = (uint32_t)(t + 1);
      while (__hip_atomic_load(&flags[(tid & 31) * 16],
                               __ATOMIC_RELAXED, __HIP_MEMORY_SCOPE_AGENT) < tgt)
        __builtin_amdgcn_s_sleep(1);
    }
    __syncthreads();

    // re-import full h state via device-scope coherent 8B loads
    {
      const unsigned long long* hxr =
          (const unsigned long long*)(hx + ((t + 1) & 1) * (B_SZ * K2));
      unsigned long long v[16];
      #pragma unroll
      for (int p = 0; p < 16; ++p)
        v[p] = __hip_atomic_load(&hxr[tid + p * 512],
                                 __ATOMIC_RELAXED, __HIP_MEMORY_SCOPE_AGENT);
      #pragma unroll
      for (int p = 0; p < 16; ++p) {
        const int q  = tid + p * 512;          // uint2 chunk id, 8192 total
        const int bb = q >> 8;                 // 256 chunks per b-row
        const int k2 = (q & 255) * 2;
        *(uint2*)&h_lds[bb * HPAD + k2] = make_uint2((uint32_t)v[p],
                                                     (uint32_t)(v[p] >> 32));
      }
    }
    __syncthreads();
  }

  *(float2*)(last_state + b * HID + j0) = hreg;
}

extern "C" void kernel_launch(void* const* d_in, const int* in_sizes, int n_in,
                              void* d_out, int out_size, void* d_ws, size_t ws_size,
                              hipStream_t stream)
{
  const float* inputs    = (const float*)d_in[0];
  const float* timespans = (const float*)d_in[1];
  const float* init_h    = (const float*)d_in[2];
  const float* W_in      = (const float*)d_in[3];
  const float* b_in      = (const float*)d_in[4];
  const float* W_x       = (const float*)d_in[5];
  const float* W_h       = (const float*)d_in[6];
  const float* b_cell    = (const float*)d_in[7];
  const float* tau       = (const float*)d_in[8];
  const float* A         = (const float*)d_in[9];
  const float* W_out     = (const float*)d_in[10];
  const float* b_out     = (const float*)d_in[11];
  float* out = (float*)d_out;

  float*    ws    = (float*)d_ws;
  float*    pre   = ws;                                  // T*B*HID f32
  float*    hseq  = pre   + (size_t)T_SZ * B_SZ * HID;   // T*B*MOT f32
  float*    WxiWp = hseq  + (size_t)T_SZ * B_SZ * MOT;   // HID*IN_SZ (Wxi f32, then Wp16 u32)
  float*    beff  = WxiWp + (size_t)HID * IN_SZ;         // HID
  uint32_t* hx    = (uint32_t*)(beff + HID);             // 2*B*K2
  uint32_t* flags = hx + 2 * B_SZ * K2;                  // NBLK*16 u32

  // K0: Wxi = W_x @ W_in  (fold input projection into cell GEMM)
  gemm_tiled<false><<<dim3(IN_SZ / 64, HID / 64), 256, 0, stream>>>(
      W_x, W_in, nullptr, WxiWp, HID, IN_SZ, SEN, SEN,
      1 << 30, (long long)IN_SZ, 0LL);

  bias_eff_kernel<<<HID / 256, 256, 0, stream>>>(W_x, b_in, b_cell, beff);

  // K1: pre[t][b][h] = inputs[r=b*T+t,:] @ Wxi^T + beff
  gemm_tiled<true><<<dim3(HID / 64, (B_SZ * T_SZ) / 64), 256, 0, stream>>>(
      inputs, WxiWp, beff, pre, B_SZ * T_SZ, HID, IN_SZ, IN_SZ,
      T_SZ, (long long)B_SZ * HID, (long long)HID);

  // K2a: pack W_h -> f16x2 (overwrites Wxi slot; stream order makes it safe)
  pack_wh16_kernel<<<(HID * K2) / 256, 256, 0, stream>>>(W_h, (uint32_t*)WxiWp);

  // K2b: zero arrival flags (re-zeroed every replay)
  (void)hipMemsetAsync(flags, 0, NBLK * 16 * sizeof(uint32_t), stream);

  // K2c: the scan — cooperative launch guarantees co-residency of 32 blocks
  {
    const uint32_t* Wp16c = (const uint32_t*)WxiWp;
    float* last_state = out + (size_t)B_SZ * T_SZ * OUT_SZ;
    void* args[] = {
      (void*)&init_h, (void*)&Wp16c, (void*)&pre, (void*)&timespans,
      (void*)&A, (void*)&tau, (void*)&hseq, (void*)&hx, (void*)&flags,
      (void*)&last_state
    };
    (void)hipLaunchCooperativeKernel((void*)scan_x_kernel, dim3(NBLK), dim3(512),
                                     args, 0, stream);
  }

  // K3: out[b][t][o] = hseq[r=t*B+b, :MOT] @ W_out^T + b_out
  gemm_tiled<true><<<dim3(OUT_SZ / 64, (B_SZ * T_SZ) / 64), 256, 0, stream>>>(
      hseq, W_out, b_out, out, B_SZ * T_SZ, OUT_SZ, MOT, MOT,
      B_SZ, (long long)T_SZ * OUT_SZ, (long long)OUT_SZ);
}

// Round 8
// 5462.836 us; speedup vs baseline: 2.3256x; 2.3256x over previous
//
#include <hip/hip_runtime.h>
#include <math.h>

#define B_SZ   32
#define T_SZ   1024
#define IN_SZ  512
#define SEN    512
#define HID    1024
#define MOT    512
#define OUT_SZ 512

#define NBLK   32          // scan blocks (j-slices)
#define JSL    32          // j's per block
#define K2     512         // f16-pair words per h row
#define HPAD   516         // padded LDS row stride in dwords (≡4 mod 32: 8-lane groups tile banks)
#define WPAD   516

typedef __fp16  f16x8 __attribute__((ext_vector_type(8)));
typedef float   f32x4 __attribute__((ext_vector_type(4)));

__device__ inline uint32_t pk16(float a, float b) {
  auto p = __builtin_amdgcn_cvt_pkrtz(a, b);
  return __builtin_bit_cast(uint32_t, p);
}

// ---------------------------------------------------------------------------
// Generic tiled f32 GEMM:  C[scatter(r), c] = sum_k A[r,k] * op(B)[k,c] + bias[c]
//   TB=true : Bm is [N][K] row-major (A @ B^T);  TB=false: Bm is [K][N] (A @ B)
//   C address for row r, col c:  (r % P)*S1 + (r / P)*S2 + c
// ---------------------------------------------------------------------------
template<bool TB>
__global__ __launch_bounds__(256) void gemm_tiled(
    const float* __restrict__ A, const float* __restrict__ Bm,
    const float* __restrict__ bias, float* __restrict__ C,
    int M, int N, int K, int lda,
    int P, long long S1, long long S2)
{
  __shared__ float As[16][64 + 1];
  __shared__ float Bs[16][64 + 1];
  const int tid = threadIdx.x;
  const int n0 = blockIdx.x * 64;
  const int r0 = blockIdx.y * 64;
  const int ty = tid / 16;
  const int tx = tid % 16;

  float acc[4][4] = {};

  for (int k0 = 0; k0 < K; k0 += 16) {
    {
      const int kk = tid % 16, m0 = tid / 16;
      #pragma unroll
      for (int i = 0; i < 4; i++) {
        const int m = m0 + i * 16;
        As[kk][m] = A[(long long)(r0 + m) * lda + k0 + kk];
      }
    }
    if (TB) {
      const int kk = tid % 16, nl0 = tid / 16;
      #pragma unroll
      for (int i = 0; i < 4; i++) {
        const int n = nl0 + i * 16;
        Bs[kk][n] = Bm[(long long)(n0 + n) * K + k0 + kk];
      }
    } else {
      const int nl = tid % 64, kk0 = tid / 64;
      #pragma unroll
      for (int i = 0; i < 4; i++) {
        const int kk = kk0 + i * 4;
        Bs[kk][nl] = Bm[(long long)(k0 + kk) * N + n0 + nl];
      }
    }
    __syncthreads();

    #pragma unroll
    for (int kk = 0; kk < 16; kk++) {
      float av[4], bv[4];
      #pragma unroll
      for (int i = 0; i < 4; i++) av[i] = As[kk][ty * 4 + i];
      #pragma unroll
      for (int j = 0; j < 4; j++) bv[j] = Bs[kk][tx * 4 + j];
      #pragma unroll
      for (int i = 0; i < 4; i++)
        #pragma unroll
        for (int j = 0; j < 4; j++)
          acc[i][j] += av[i] * bv[j];
    }
    __syncthreads();
  }

  #pragma unroll
  for (int i = 0; i < 4; i++) {
    const int r = r0 + ty * 4 + i;
    const long long base = (long long)(r % P) * S1 + (long long)(r / P) * S2;
    #pragma unroll
    for (int j = 0; j < 4; j++) {
      const int c = n0 + tx * 4 + j;
      float v = acc[i][j];
      if (bias) v += bias[c];
      C[base + c] = v;
    }
  }
}

// bias_eff[h] = b_cell[h] + dot(W_x[h,:], b_in)
__global__ void bias_eff_kernel(const float* __restrict__ Wx,
                                const float* __restrict__ b_in,
                                const float* __restrict__ b_cell,
                                float* __restrict__ bias_eff)
{
  const int h = blockIdx.x * 256 + threadIdx.x;
  float s = b_cell[h];
  for (int k = 0; k < SEN; k++) s += Wx[h * SEN + k] * b_in[k];
  bias_eff[h] = s;
}

// Pack W_h f32 [j][k] -> Wp16 u32 [j][k2]: pack(f16(W[j][2k2]), f16(W[j][2k2+1]))
__global__ __launch_bounds__(256) void pack_wh16_kernel(
    const float* __restrict__ Wh, uint32_t* __restrict__ Wp16)
{
  const int idx = blockIdx.x * 256 + threadIdx.x;       // j*K2 + k2
  const float2 v = *(const float2*)(Wh + (size_t)idx * 2);
  Wp16[idx] = pk16(v.x, v.y);
}

// ---------------------------------------------------------------------------
// Scan v6 (MFMA): 32 blocks x 256 threads (4 waves). Block bk owns j-rows
// [bk*32, bk*32+32). Per step each block computes the 32x32 C-tile
// h[32b x 1024k] @ Wslice^T via mfma_f32_16x16x32_f16:
//   wave w = quadrant (qr=w>>1 over b, qc=w&1 over j); 32 K-iterations.
//   A-frag: lane holds h[qr*16 + (l&15)][k: kk*32+(l>>4)*8 ..+7] (one uint4)
//   B-frag: lane holds W[qc*16 + (l&15)][same k range]        (one uint4)
//   C:      lane holds rows (l>>4)*4+r (r=0..3), col l&15  [m89 layout]
// Thread statically owns 4 (b,j) cells -> exact f32 h_old in registers.
// Exchange/barrier: proven flag-line protocol (R6/R7), f16-pair hx buffer.
// ---------------------------------------------------------------------------
__global__ __launch_bounds__(256) void scan_x_kernel(
    const float* __restrict__ init_h,
    const uint32_t* __restrict__ Wp16,   // [HID][K2]
    const float* __restrict__ pre,       // [T][B][HID]
    const float* __restrict__ tsp,       // [B][T]
    const float* __restrict__ Avec,
    const float* __restrict__ tau,
    float* __restrict__ hseq,            // [T][B][MOT]
    uint32_t* __restrict__ hx,           // [2][B][K2] exchange
    uint32_t* __restrict__ flags,        // [NBLK][16] arrival flags (pre-zeroed)
    float* __restrict__ last_state)      // [B][HID]
{
  __shared__ uint32_t w_lds[JSL * WPAD];   // 66 KB
  __shared__ uint32_t h_lds[B_SZ * HPAD];  // 66 KB

  const int bk   = blockIdx.x;
  const int tid  = threadIdx.x;
  const int wv   = tid >> 6;               // 0..3
  const int lane = tid & 63;
  const int qr   = wv >> 1;                // b-half
  const int qc   = wv & 1;                 // j-half
  const int row16 = lane & 15;
  const int kg    = lane >> 4;             // 0..3

  const int j_loc  = qc * 16 + row16;      // 0..31 (fixed per thread)
  const int j_glob = bk * JSL + j_loc;
  const int b0     = qr * 16 + kg * 4;     // first of 4 owned b's

  // stage weight slice (once), row-padded
  {
    const uint32_t* src = Wp16 + (size_t)bk * JSL * K2;
    for (int i = tid; i < JSL * K2; i += 256)
      w_lds[(i >> 9) * WPAD + (i & (K2 - 1))] = src[i];
  }
  // stage initial h (f32 -> f16x2)
  for (int i = tid; i < B_SZ * K2; i += 256) {
    const int bb = i >> 9, k2 = i & (K2 - 1);
    const float2 v = *(const float2*)(init_h + bb * HID + 2 * k2);
    h_lds[bb * HPAD + k2] = pk16(v.x, v.y);
  }

  const float a_j  = Avec[j_glob];
  const float it_j = 1.f / tau[j_glob];
  float h_old[4];
  #pragma unroll
  for (int r = 0; r < 4; ++r) h_old[r] = init_h[(b0 + r) * HID + j_glob];

  __syncthreads();

  // prefetch step-0 pre/ts
  float prevC[4], tsC[4];
  #pragma unroll
  for (int r = 0; r < 4; ++r) {
    prevC[r] = pre[(size_t)(b0 + r) * HID + j_glob];
    tsC[r]   = tsp[(b0 + r) * T_SZ + 0];
  }

  const uint32_t* arow = &h_lds[(qr * 16 + row16) * HPAD];
  const uint32_t* brow = &w_lds[j_loc * WPAD];

  for (int t = 0; t < T_SZ; ++t) {
    f32x4 acc = {0.f, 0.f, 0.f, 0.f};
    #pragma unroll 8
    for (int kk = 0; kk < 32; ++kk) {
      const uint4 av = *(const uint4*)(arow + kk * 16 + kg * 4);
      const uint4 bv = *(const uint4*)(brow + kk * 16 + kg * 4);
      acc = __builtin_amdgcn_mfma_f32_16x16x32_f16(
          __builtin_bit_cast(f16x8, av), __builtin_bit_cast(f16x8, bv),
          acc, 0, 0, 0);
    }

    // liquid update for the 4 owned (b, j) cells
    float hn[4];
    #pragma unroll
    for (int r = 0; r < 4; ++r) {
      const float z = acc[r] + prevC[r];
      const float f = 1.f / (1.f + __expf(-z));
      hn[r] = (h_old[r] + tsC[r] * f * a_j) / (1.f + tsC[r] * (it_j + f));
      h_old[r] = hn[r];
    }

    // publish: pack (j, j^1) pairs via shfl_xor; even j-lanes store dwords
    uint32_t* hxw = hx + ((t + 1) & 1) * (B_SZ * K2);
    #pragma unroll
    for (int r = 0; r < 4; ++r) {
      const float partner = __shfl_xor(hn[r], 1);
      if ((row16 & 1) == 0)
        __hip_atomic_store(&hxw[(b0 + r) * K2 + bk * (JSL / 2) + (j_loc >> 1)],
                           pk16(hn[r], partner),
                           __ATOMIC_RELAXED, __HIP_MEMORY_SCOPE_AGENT);
    }
    if (bk < 16) {   // motor half -> hseq f32 (coalesced 64B runs)
      #pragma unroll
      for (int r = 0; r < 4; ++r)
        hseq[(size_t)t * (B_SZ * MOT) + (b0 + r) * MOT + j_glob] = hn[r];
    }

    // prefetch next step's pre/ts while stores drain
    const int tn = (t + 1 < T_SZ) ? t + 1 : t;
    #pragma unroll
    for (int r = 0; r < 4; ++r) {
      prevC[r] = pre[(size_t)tn * (B_SZ * HID) + (b0 + r) * HID + j_glob];
      tsC[r]   = tsp[(b0 + r) * T_SZ + tn];
    }

    __syncthreads();   // (a) h_lds reads done  (b) vmcnt drained -> hx visible

    if (tid == 0)
      __hip_atomic_store(&flags[bk * 16], (uint32_t)(t + 1),
                         __ATOMIC_RELAXED, __HIP_MEMORY_SCOPE_AGENT);
    if (tid < 64) {
      const uint32_t tgt = (uint32_t)(t + 1);
      while (__hip_atomic_load(&flags[(tid & 31) * 16],
                               __ATOMIC_RELAXED, __HIP_MEMORY_SCOPE_AGENT) < tgt)
        __builtin_amdgcn_s_sleep(1);
    }
    __syncthreads();

    // re-import full h state (64 KB) via device-scope coherent 8B loads
    {
      const unsigned long long* hxr =
          (const unsigned long long*)(hx + ((t + 1) & 1) * (B_SZ * K2));
      unsigned long long v[32];
      #pragma unroll
      for (int p = 0; p < 32; ++p)
        v[p] = __hip_atomic_load(&hxr[tid + p * 256],
                                 __ATOMIC_RELAXED, __HIP_MEMORY_SCOPE_AGENT);
      #pragma unroll
      for (int p = 0; p < 32; ++p) {
        const int q  = tid + p * 256;          // uint2 chunk id, 8192 total
        const int bb = q >> 8;                 // 256 chunks per b-row
        const int k2 = (q & 255) * 2;
        *(uint2*)&h_lds[bb * HPAD + k2] = make_uint2((uint32_t)v[p],
                                                     (uint32_t)(v[p] >> 32));
      }
    }
    __syncthreads();
  }

  #pragma unroll
  for (int r = 0; r < 4; ++r)
    last_state[(b0 + r) * HID + j_glob] = h_old[r];
}

extern "C" void kernel_launch(void* const* d_in, const int* in_sizes, int n_in,
                              void* d_out, int out_size, void* d_ws, size_t ws_size,
                              hipStream_t stream)
{
  const float* inputs    = (const float*)d_in[0];
  const float* timespans = (const float*)d_in[1];
  const float* init_h    = (const float*)d_in[2];
  const float* W_in      = (const float*)d_in[3];
  const float* b_in      = (const float*)d_in[4];
  const float* W_x       = (const float*)d_in[5];
  const float* W_h       = (const float*)d_in[6];
  const float* b_cell    = (const float*)d_in[7];
  const float* tau       = (const float*)d_in[8];
  const float* A         = (const float*)d_in[9];
  const float* W_out     = (const float*)d_in[10];
  const float* b_out     = (const float*)d_in[11];
  float* out = (float*)d_out;

  float*    ws    = (float*)d_ws;
  float*    pre   = ws;                                  // T*B*HID f32
  float*    hseq  = pre   + (size_t)T_SZ * B_SZ * HID;   // T*B*MOT f32
  float*    WxiWp = hseq  + (size_t)T_SZ * B_SZ * MOT;   // HID*IN_SZ (Wxi f32, then Wp16 u32)
  float*    beff  = WxiWp + (size_t)HID * IN_SZ;         // HID
  uint32_t* hx    = (uint32_t*)(beff + HID);             // 2*B*K2
  uint32_t* flags = hx + 2 * B_SZ * K2;                  // NBLK*16 u32

  // K0: Wxi = W_x @ W_in  (fold input projection into cell GEMM)
  gemm_tiled<false><<<dim3(IN_SZ / 64, HID / 64), 256, 0, stream>>>(
      W_x, W_in, nullptr, WxiWp, HID, IN_SZ, SEN, SEN,
      1 << 30, (long long)IN_SZ, 0LL);

  bias_eff_kernel<<<HID / 256, 256, 0, stream>>>(W_x, b_in, b_cell, beff);

  // K1: pre[t][b][h] = inputs[r=b*T+t,:] @ Wxi^T + beff
  gemm_tiled<true><<<dim3(HID / 64, (B_SZ * T_SZ) / 64), 256, 0, stream>>>(
      inputs, WxiWp, beff, pre, B_SZ * T_SZ, HID, IN_SZ, IN_SZ,
      T_SZ, (long long)B_SZ * HID, (long long)HID);

  // K2a: pack W_h -> f16x2 (overwrites Wxi slot; stream order makes it safe)
  pack_wh16_kernel<<<(HID * K2) / 256, 256, 0, stream>>>(W_h, (uint32_t*)WxiWp);

  // K2b: zero arrival flags (re-zeroed every replay)
  (void)hipMemsetAsync(flags, 0, NBLK * 16 * sizeof(uint32_t), stream);

  // K2c: the scan — cooperative launch guarantees co-residency of 32 blocks
  {
    const uint32_t* Wp16c = (const uint32_t*)WxiWp;
    float* last_state = out + (size_t)B_SZ * T_SZ * OUT_SZ;
    void* args[] = {
      (void*)&init_h, (void*)&Wp16c, (void*)&pre, (void*)&timespans,
      (void*)&A, (void*)&tau, (void*)&hseq, (void*)&hx, (void*)&flags,
      (void*)&last_state
    };
    (void)hipLaunchCooperativeKernel((void*)scan_x_kernel, dim3(NBLK), dim3(256),
                                     args, 0, stream);
  }

  // K3: out[b][t][o] = hseq[r=t*B+b, :MOT] @ W_out^T + b_out
  gemm_tiled<true><<<dim3(OUT_SZ / 64, (B_SZ * T_SZ) / 64), 256, 0, stream>>>(
      hseq, W_out, b_out, out, B_SZ * T_SZ, OUT_SZ, MOT, MOT,
      B_SZ, (long long)T_SZ * OUT_SZ, (long long)OUT_SZ);
}